// Round 6
// baseline (403.690 us; speedup 1.0000x reference)
//
#include <hip/hip_runtime.h>

#define N_NODES 100000
#define E_EDGES 1600000
#define DIM     128
#define PAD     64           // padded-CSR row stride (max deg; Poisson(16) -> P(>=64)~1e-21)

// Workspace layout (bytes), total ~51.7 MiB:
#define HB_OFF   0            // h packed bf16: N*64 u32 = 25,600,000
#define WTB_OFF  25600000     // WcatT bf16 B-fragment layout: 16384 u32 = 65,536
#define DEG_OFF  25665536     // N int = 400,000
#define PSRC_OFF 26065536     // padded CSR: N*64 int = 25,600,000 -> end 51,665,536

typedef __attribute__((ext_vector_type(8))) short short8;
typedef __attribute__((ext_vector_type(4))) float floatx4;

// ---------- bf16 pack/unpack (RNE) ----------
__device__ __forceinline__ unsigned bf16pack(float a, float b) {
  unsigned ua = __float_as_uint(a); ua += 0x7fffu + ((ua >> 16) & 1u);
  unsigned ub = __float_as_uint(b); ub += 0x7fffu + ((ub >> 16) & 1u);
  return (ua >> 16) | (ub & 0xffff0000u);
}
__device__ __forceinline__ float2 bf16unpack(unsigned p) {
  return make_float2(__uint_as_float(p << 16), __uint_as_float(p & 0xffff0000u));
}

// ------------- prep: LN+ReLU -> hb; count+fill padded CSR; weight pack -------
// The atomicAdd return IS the CSR slot -> no scan, no rank, no fill kernel.
__global__ __launch_bounds__(256) void k_prep(const float* __restrict__ x,
                                              const float* __restrict__ lw,
                                              const float* __restrict__ lb,
                                              const float* __restrict__ Wl,
                                              const float* __restrict__ Wr,
                                              const int* __restrict__ ei,
                                              unsigned* __restrict__ hb,
                                              int* __restrict__ deg,
                                              int* __restrict__ psrc,
                                              unsigned* __restrict__ wtb) {
  int gid = blockIdx.x * 256 + threadIdx.x;

  // --- LN+ReLU (4 rows/block, one wave per row) ---
  {
    int row  = blockIdx.x * 4 + (threadIdx.x >> 6);
    int lane = threadIdx.x & 63;
    float2 v = ((const float2*)(x + (size_t)row * DIM))[lane];
    float s  = v.x + v.y;
    float sq = v.x * v.x + v.y * v.y;
    #pragma unroll
    for (int off = 32; off > 0; off >>= 1) {
      s  += __shfl_xor(s, off);
      sq += __shfl_xor(sq, off);
    }
    float mu  = s * (1.0f / 128.0f);
    float var = sq * (1.0f / 128.0f) - mu * mu;
    float rs  = rsqrtf(var + 1e-5f);
    float2 w = ((const float2*)lw)[lane];
    float2 b = ((const float2*)lb)[lane];
    float ox = fmaxf((v.x - mu) * rs * w.x + b.x, 0.0f);
    float oy = fmaxf((v.y - mu) * rs * w.y + b.y, 0.0f);
    hb[(size_t)row * 64 + lane] = bf16pack(ox, oy);
  }

  // --- count + padded-CSR fill (4 edges/thread) ---
  if (gid < E_EDGES / 4) {
    int4 s = ((const int4*)ei)[gid];
    int4 d = ((const int4*)(ei + E_EDGES))[gid];
    int r0 = atomicAdd(&deg[d.x], 1);
    int r1 = atomicAdd(&deg[d.y], 1);
    int r2 = atomicAdd(&deg[d.z], 1);
    int r3 = atomicAdd(&deg[d.w], 1);
    if (r0 < PAD) psrc[d.x * PAD + r0] = s.x;
    if (r1 < PAD) psrc[d.y * PAD + r1] = s.y;
    if (r2 < PAD) psrc[d.z * PAD + r2] = s.z;
    if (r3 < PAD) psrc[d.w * PAD + r3] = s.w;
  }

  // --- weight pack (bf16, MFMA B-fragment layout) ---
  // u32 idx i = kb*2048 + c*16 + q*4 + j2 -> (k = kb*32 + q*8 + 2*j2 {,+1}, col c)
  if (gid < 16384) {
    int j2 = gid & 3;
    int q  = (gid >> 2) & 3;
    int c  = (gid >> 4) & 127;
    int kb = gid >> 11;
    int k0 = kb * 32 + q * 8 + j2 * 2;
    int k1 = k0 + 1;
    float v0 = (k0 < 128) ? Wl[c * 128 + k0] : Wr[c * 128 + (k0 - 128)];
    float v1 = (k1 < 128) ? Wl[c * 128 + k1] : Wr[c * 128 + (k1 - 128)];
    wtb[gid] = bf16pack(v0, v1);
  }
}

// ------------- fused gather + mean + bf16 MFMA GEMM --------------------------
// Block = 64 rows (4 waves x 16). Each wave gathers ITS OWN 16 GEMM rows into
// a per-wave LDS slice (pitch 68 u32: frag reads conflict-spread), then runs
// the 16x128 MFMA tile: A = [LDS agg | global hb], B = pre-packed wtb.
#define GPITCH 68
__global__ __launch_bounds__(256) void k_gather_gemm(const unsigned* __restrict__ hb,
                                                     const int* __restrict__ deg,
                                                     const int* __restrict__ psrc,
                                                     const unsigned* __restrict__ wtb,
                                                     const float* __restrict__ bl,
                                                     float* __restrict__ out) {
  __shared__ unsigned At[64 * GPITCH];   // 17,408 B
  int wave = threadIdx.x >> 6;
  int lane = threadIdx.x & 63;
  int r0blk = blockIdx.x * 64;
  int r0w   = r0blk + wave * 16;

  // ---- gather phase: 16 nodes per wave ----
  for (int rr = 0; rr < 16; ++rr) {
    int n = r0w + rr;
    if (n > N_NODES - 1) n = N_NODES - 1;      // tail clamp (stores guarded later)
    int dg = __builtin_amdgcn_readfirstlane(deg[n]);
    int m  = dg < PAD ? dg : PAD;
    const int* row = psrc + n * PAD;
    int full = m & ~7;
    float ax = 0.0f, ay = 0.0f;
    for (int j0 = 0; j0 < full; j0 += 8) {
      #pragma unroll
      for (int i = 0; i < 8; ++i) {
        int s = row[j0 + i];                   // wave-uniform -> scalar load
        unsigned p = hb[(size_t)s * 64 + lane];
        float2 v = bf16unpack(p);
        ax += v.x; ay += v.y;
      }
    }
    for (int j = full; j < m; ++j) {
      int s = row[j];
      unsigned p = hb[(size_t)s * 64 + lane];
      float2 v = bf16unpack(p);
      ax += v.x; ay += v.y;
    }
    float inv = 1.0f / fmaxf((float)dg, 1.0f);
    At[(wave * 16 + rr) * GPITCH + lane] = bf16pack(ax * inv, ay * inv);
  }
  __syncthreads();

  // ---- GEMM phase ----
  int m = lane & 15;
  int q = lane >> 4;
  int rowA = r0w + m;
  if (rowA > N_NODES - 1) rowA = N_NODES - 1;

  short8 afrag[8];
  // kb 0..3 (agg half) from LDS
  #pragma unroll
  for (int kb = 0; kb < 4; ++kb) {
    uint4 u = *(const uint4*)&At[(wave * 16 + m) * GPITCH + kb * 16 + q * 4];
    afrag[kb] = *(short8*)&u;
  }
  // kb 4..7 (h half) direct from global
  const uint4* hr = (const uint4*)(hb + (size_t)rowA * 64);
  #pragma unroll
  for (int kb = 0; kb < 4; ++kb) {
    uint4 u = hr[kb * 4 + q];
    afrag[kb + 4] = *(short8*)&u;
  }

  const uint4* b4 = (const uint4*)wtb;
  #pragma unroll
  for (int ct = 0; ct < 8; ++ct) {
    int c = ct * 16 + m;
    floatx4 acc = {0.0f, 0.0f, 0.0f, 0.0f};
    #pragma unroll
    for (int kb = 0; kb < 8; ++kb) {
      uint4 u = b4[kb * 512 + c * 4 + q];
      short8 bfrag = *(short8*)&u;
      acc = __builtin_amdgcn_mfma_f32_16x16x32_bf16(afrag[kb], bfrag, acc, 0, 0, 0);
    }
    float bias = bl[c];
    #pragma unroll
    for (int reg = 0; reg < 4; ++reg) {
      int r = r0w + q * 4 + reg;
      if (r < N_NODES) out[(size_t)r * DIM + c] = acc[reg] + bias;
    }
  }
}

extern "C" void kernel_launch(void* const* d_in, const int* in_sizes, int n_in,
                              void* d_out, int out_size, void* d_ws, size_t ws_size,
                              hipStream_t stream) {
  const float* x  = (const float*)d_in[0];
  const int*   ei = (const int*)d_in[1];   // [2, E] int32
  const float* lw = (const float*)d_in[2];
  const float* lb = (const float*)d_in[3];
  const float* Wl = (const float*)d_in[4];
  const float* bl = (const float*)d_in[5];
  const float* Wr = (const float*)d_in[6];
  float* out = (float*)d_out;

  char* ws = (char*)d_ws;
  unsigned* hb   = (unsigned*)(ws + HB_OFF);
  unsigned* wtb  = (unsigned*)(ws + WTB_OFF);
  int*      deg  = (int*)(ws + DEG_OFF);
  int*      psrc = (int*)(ws + PSRC_OFF);

  hipMemsetAsync(deg, 0, (size_t)N_NODES * 4, stream);

  k_prep<<<N_NODES / 4, 256, 0, stream>>>(x, lw, lb, Wl, Wr, ei, hb, deg, psrc, wtb);
  k_gather_gemm<<<(N_NODES + 63) / 64, 256, 0, stream>>>(hb, deg, psrc, wtb, bl, out);
}

// Round 7
// 318.044 us; speedup vs baseline: 1.2693x; 1.2693x over previous
//
#include <hip/hip_runtime.h>

#define N_NODES 100000
#define E_EDGES 1600000
#define DIM     128

// Workspace layout (bytes), total ~65.3 MiB:
#define HB_OFF   0            // h packed bf16: N*64 u32 = 25,600,000
#define AGGB_OFF 25600000     // mean-agg packed bf16: N*64 u32 = 25,600,000
#define WTB_OFF  51200000     // WcatT bf16 B-fragment layout: 16384 u32 = 65,536
#define DEG_OFF  51265536     // N int
#define OFFS_OFF 51665536     // N+1 int (pad 8)
#define BSUM_OFF 52065544     // 98 int (pad 512)
#define SRC_OFF  52066056     // E int = 6,400,000
#define RANK_OFF 58466056     // E int = 6,400,000 -> end 64,866,056

#define SCAN_BLOCKS 98

typedef __attribute__((ext_vector_type(8))) short short8;
typedef __attribute__((ext_vector_type(4))) float floatx4;

// ---------- bf16 pack/unpack (RNE) ----------
__device__ __forceinline__ unsigned bf16pack(float a, float b) {
  unsigned ua = __float_as_uint(a); ua += 0x7fffu + ((ua >> 16) & 1u);
  unsigned ub = __float_as_uint(b); ub += 0x7fffu + ((ub >> 16) & 1u);
  return (ua >> 16) | (ub & 0xffff0000u);
}
__device__ __forceinline__ float2 bf16unpack(unsigned p) {
  return make_float2(__uint_as_float(p << 16), __uint_as_float(p & 0xffff0000u));
}

// ------------- prep: LayerNorm+ReLU -> hb, degree+rank, weight pack ----------
__global__ __launch_bounds__(256) void k_prep(const float* __restrict__ x,
                                              const float* __restrict__ lw,
                                              const float* __restrict__ lb,
                                              const float* __restrict__ Wl,
                                              const float* __restrict__ Wr,
                                              const int* __restrict__ ei,
                                              unsigned* __restrict__ hb,
                                              int* __restrict__ deg,
                                              int* __restrict__ rank,
                                              unsigned* __restrict__ wtb) {
  int gid = blockIdx.x * 256 + threadIdx.x;

  // --- LN+ReLU ---
  {
    int row  = blockIdx.x * 4 + (threadIdx.x >> 6);
    int lane = threadIdx.x & 63;
    float2 v = ((const float2*)(x + (size_t)row * DIM))[lane];
    float s  = v.x + v.y;
    float sq = v.x * v.x + v.y * v.y;
    #pragma unroll
    for (int off = 32; off > 0; off >>= 1) {
      s  += __shfl_xor(s, off);
      sq += __shfl_xor(sq, off);
    }
    float mu  = s * (1.0f / 128.0f);
    float var = sq * (1.0f / 128.0f) - mu * mu;
    float rs  = rsqrtf(var + 1e-5f);
    float2 w = ((const float2*)lw)[lane];
    float2 b = ((const float2*)lb)[lane];
    float ox = fmaxf((v.x - mu) * rs * w.x + b.x, 0.0f);
    float oy = fmaxf((v.y - mu) * rs * w.y + b.y, 0.0f);
    hb[(size_t)row * 64 + lane] = bf16pack(ox, oy);
  }

  // --- degree histogram + per-edge rank (4 edges/thread, coalesced rank) ---
  if (gid < E_EDGES / 4) {
    int4 d = ((const int4*)(ei + E_EDGES))[gid];
    int4 r;
    r.x = atomicAdd(&deg[d.x], 1);
    r.y = atomicAdd(&deg[d.y], 1);
    r.z = atomicAdd(&deg[d.z], 1);
    r.w = atomicAdd(&deg[d.w], 1);
    ((int4*)rank)[gid] = r;
  }

  // --- weight pack (bf16, B-fragment layout) ---
  if (gid < 16384) {
    int j2 = gid & 3;
    int q  = (gid >> 2) & 3;
    int c  = (gid >> 4) & 127;
    int kb = gid >> 11;
    int k0 = kb * 32 + q * 8 + j2 * 2;
    int k1 = k0 + 1;
    float v0 = (k0 < 128) ? Wl[c * 128 + k0] : Wr[c * 128 + (k0 - 128)];
    float v1 = (k1 < 128) ? Wl[c * 128 + k1] : Wr[c * 128 + (k1 - 128)];
    wtb[gid] = bf16pack(v0, v1);
  }
}

// ---------------- scan stage 1: per-block exclusive scan (1024 elems) --------
__global__ __launch_bounds__(256) void k_scan1(const int* __restrict__ deg,
                                               int* __restrict__ offs,
                                               int* __restrict__ bsum) {
  __shared__ int s[256];
  int t = threadIdx.x;
  int base = blockIdx.x * 1024 + t * 4;
  int a0 = (base + 0 < N_NODES) ? deg[base + 0] : 0;
  int a1 = (base + 1 < N_NODES) ? deg[base + 1] : 0;
  int a2 = (base + 2 < N_NODES) ? deg[base + 2] : 0;
  int a3 = (base + 3 < N_NODES) ? deg[base + 3] : 0;
  s[t] = a0 + a1 + a2 + a3;
  __syncthreads();
  #pragma unroll
  for (int off = 1; off < 256; off <<= 1) {
    int x = (t >= off) ? s[t - off] : 0;
    __syncthreads();
    s[t] += x;
    __syncthreads();
  }
  int excl = (t > 0) ? s[t - 1] : 0;
  if (t == 255) bsum[blockIdx.x] = s[255];
  if (base + 0 < N_NODES) offs[base + 0] = excl;
  if (base + 1 < N_NODES) offs[base + 1] = excl + a0;
  if (base + 2 < N_NODES) offs[base + 2] = excl + a0 + a1;
  if (base + 3 < N_NODES) offs[base + 3] = excl + a0 + a1 + a2;
}

// -------- scan stage 2+3 fused: each block re-scans 98 bsums locally ---------
__global__ __launch_bounds__(256) void k_scan23(int* __restrict__ offs,
                                                const int* __restrict__ bsum) {
  __shared__ int s[128];
  int t = threadIdx.x;
  if (t < 128) s[t] = (t < SCAN_BLOCKS) ? bsum[t] : 0;
  __syncthreads();
  if (t < 128) {
    #pragma unroll
    for (int off = 1; off < 128; off <<= 1) {
      int x = (t >= off) ? s[t - off] : 0;
      __syncthreads();
      s[t] += x;
      __syncthreads();
    }
  } else {
    #pragma unroll
    for (int off = 1; off < 128; off <<= 1) { __syncthreads(); __syncthreads(); }
  }
  int blk = blockIdx.x;
  int base = (blk > 0) ? s[blk - 1] : 0;
  #pragma unroll
  for (int u = 0; u < 4; ++u) {
    int i = blk * 1024 + t * 4 + u;
    if (i < N_NODES) offs[i] += base;
    if (i == N_NODES) offs[N_NODES] = E_EDGES;
  }
}

// ---------------- CSR fill: atomic-free via precomputed rank -----------------
__global__ __launch_bounds__(256) void k_fill(const int* __restrict__ ei,
                                              const int* __restrict__ offs,
                                              const int* __restrict__ rank,
                                              int* __restrict__ srcidx) {
  int i = blockIdx.x * 256 + threadIdx.x;
  if (i >= E_EDGES / 4) return;
  int4 s = ((const int4*)ei)[i];
  int4 d = ((const int4*)(ei + E_EDGES))[i];
  int4 r = ((const int4*)rank)[i];
  srcidx[offs[d.x] + r.x] = s.x;
  srcidx[offs[d.y] + r.y] = s.y;
  srcidx[offs[d.z] + r.z] = s.z;
  srcidx[offs[d.w] + r.w] = s.w;
}

// ---------------- gather + mean -> aggb (bf16) -------------------------------
// TWO nodes per wave with interleaved load chains -> 16 outstanding 256B row
// loads per wave (was 8). Still 50K independent waves (R6 showed TLP matters).
__global__ __launch_bounds__(256) void k_gather(const unsigned* __restrict__ hb,
                                                const int* __restrict__ offs,
                                                const int* __restrict__ srcidx,
                                                unsigned* __restrict__ aggb) {
  int wave = threadIdx.x >> 6;
  int lane = threadIdx.x & 63;
  int n0 = blockIdx.x * 8 + wave * 2;
  int n1 = n0 + 1;
  int b0 = __builtin_amdgcn_readfirstlane(offs[n0]);
  int e0 = __builtin_amdgcn_readfirstlane(offs[n0 + 1]);
  int b1 = __builtin_amdgcn_readfirstlane(offs[n1]);
  int e1 = __builtin_amdgcn_readfirstlane(offs[n1 + 1]);
  int m0 = e0 - b0, m1 = e1 - b1;
  int c  = (m0 < m1 ? m0 : m1) & ~7;   // common interleaved part

  float ax0 = 0.0f, ay0 = 0.0f, ax1 = 0.0f, ay1 = 0.0f;

  // interleaved: 16 outstanding loads (8 per chain)
  for (int j = 0; j < c; j += 8) {
    unsigned p0[8], p1[8];
    #pragma unroll
    for (int i = 0; i < 8; ++i) {
      int s0 = srcidx[b0 + j + i];
      int s1 = srcidx[b1 + j + i];
      p0[i] = hb[(size_t)s0 * 64 + lane];
      p1[i] = hb[(size_t)s1 * 64 + lane];
    }
    #pragma unroll
    for (int i = 0; i < 8; ++i) {
      float2 v0 = bf16unpack(p0[i]);
      float2 v1 = bf16unpack(p1[i]);
      ax0 += v0.x; ay0 += v0.y;
      ax1 += v1.x; ay1 += v1.y;
    }
  }
  // tail of node 0
  for (int j = b0 + c; j < e0; ) {
    int rem = e0 - j;
    if (rem >= 8) {
      unsigned p[8];
      #pragma unroll
      for (int i = 0; i < 8; ++i) p[i] = hb[(size_t)srcidx[j + i] * 64 + lane];
      #pragma unroll
      for (int i = 0; i < 8; ++i) { float2 v = bf16unpack(p[i]); ax0 += v.x; ay0 += v.y; }
      j += 8;
    } else {
      float2 v = bf16unpack(hb[(size_t)srcidx[j] * 64 + lane]);
      ax0 += v.x; ay0 += v.y;
      ++j;
    }
  }
  // tail of node 1
  for (int j = b1 + c; j < e1; ) {
    int rem = e1 - j;
    if (rem >= 8) {
      unsigned p[8];
      #pragma unroll
      for (int i = 0; i < 8; ++i) p[i] = hb[(size_t)srcidx[j + i] * 64 + lane];
      #pragma unroll
      for (int i = 0; i < 8; ++i) { float2 v = bf16unpack(p[i]); ax1 += v.x; ay1 += v.y; }
      j += 8;
    } else {
      float2 v = bf16unpack(hb[(size_t)srcidx[j] * 64 + lane]);
      ax1 += v.x; ay1 += v.y;
      ++j;
    }
  }

  float inv0 = 1.0f / fmaxf((float)m0, 1.0f);
  float inv1 = 1.0f / fmaxf((float)m1, 1.0f);
  aggb[(size_t)n0 * 64 + lane] = bf16pack(ax0 * inv0, ay0 * inv0);
  aggb[(size_t)n1 * 64 + lane] = bf16pack(ax1 * inv1, ay1 * inv1);
}

// ---------------- bf16 MFMA GEMM: out = [aggb|hb] @ WcatT^T + b_l ------------
__global__ __launch_bounds__(256) void k_gemm(const unsigned* __restrict__ aggb,
                                              const unsigned* __restrict__ hb,
                                              const unsigned* __restrict__ wtb,
                                              const float* __restrict__ bl,
                                              float* __restrict__ out) {
  int wave = threadIdx.x >> 6;
  int lane = threadIdx.x & 63;
  int m = lane & 15;
  int q = lane >> 4;
  int r0 = blockIdx.x * 64 + wave * 16;
  int rowA = r0 + m;
  if (rowA > N_NODES - 1) rowA = N_NODES - 1;  // tail clamp (stores guarded)

  const uint4* ar = (const uint4*)(aggb + (size_t)rowA * 64);
  const uint4* hr = (const uint4*)(hb + (size_t)rowA * 64);
  short8 afrag[8];
  #pragma unroll
  for (int kb = 0; kb < 4; ++kb) {
    uint4 u = ar[kb * 4 + q];
    afrag[kb] = *(short8*)&u;
  }
  #pragma unroll
  for (int kb = 0; kb < 4; ++kb) {
    uint4 u = hr[kb * 4 + q];
    afrag[kb + 4] = *(short8*)&u;
  }

  const uint4* b4 = (const uint4*)wtb;
  #pragma unroll
  for (int ct = 0; ct < 8; ++ct) {
    int c = ct * 16 + m;
    floatx4 acc = {0.0f, 0.0f, 0.0f, 0.0f};
    #pragma unroll
    for (int kb = 0; kb < 8; ++kb) {
      uint4 u = b4[kb * 512 + c * 4 + q];
      short8 bfrag = *(short8*)&u;
      acc = __builtin_amdgcn_mfma_f32_16x16x32_bf16(afrag[kb], bfrag, acc, 0, 0, 0);
    }
    float bias = bl[c];
    #pragma unroll
    for (int reg = 0; reg < 4; ++reg) {
      int r = r0 + q * 4 + reg;
      if (r < N_NODES) out[(size_t)r * DIM + c] = acc[reg] + bias;
    }
  }
}

extern "C" void kernel_launch(void* const* d_in, const int* in_sizes, int n_in,
                              void* d_out, int out_size, void* d_ws, size_t ws_size,
                              hipStream_t stream) {
  const float* x  = (const float*)d_in[0];
  const int*   ei = (const int*)d_in[1];   // [2, E] int32
  const float* lw = (const float*)d_in[2];
  const float* lb = (const float*)d_in[3];
  const float* Wl = (const float*)d_in[4];
  const float* bl = (const float*)d_in[5];
  const float* Wr = (const float*)d_in[6];
  float* out = (float*)d_out;

  char* ws = (char*)d_ws;
  unsigned* hb     = (unsigned*)(ws + HB_OFF);
  unsigned* aggb   = (unsigned*)(ws + AGGB_OFF);
  unsigned* wtb    = (unsigned*)(ws + WTB_OFF);
  int*      deg    = (int*)(ws + DEG_OFF);
  int*      offs   = (int*)(ws + OFFS_OFF);
  int*      bsum   = (int*)(ws + BSUM_OFF);
  int*      srcidx = (int*)(ws + SRC_OFF);
  int*      rank   = (int*)(ws + RANK_OFF);

  hipMemsetAsync(deg, 0, (size_t)N_NODES * 4, stream);

  k_prep<<<N_NODES / 4, 256, 0, stream>>>(x, lw, lb, Wl, Wr, ei, hb, deg, rank, wtb);
  k_scan1<<<SCAN_BLOCKS, 256, 0, stream>>>(deg, offs, bsum);
  k_scan23<<<SCAN_BLOCKS, 256, 0, stream>>>(offs, bsum);
  k_fill<<<(E_EDGES / 4 + 255) / 256, 256, 0, stream>>>(ei, offs, rank, srcidx);
  k_gather<<<N_NODES / 8, 256, 0, stream>>>(hb, offs, srcidx, aggb);
  k_gemm<<<(N_NODES + 63) / 64, 256, 0, stream>>>(aggb, hb, wtb, bl, out);
}